// Round 4
// baseline (222.022 us; speedup 1.0000x reference)
//
#include <hip/hip_runtime.h>

#define P 128
#define GRID1 2048
#define BLK 256

__device__ __forceinline__ void atomicAddF(float* p, float v) {
#if defined(__HIP_DEVICE_COMPILE__)
    unsafeAtomicAdd(p, v);   // global_atomic_add_f32 on gfx950
#else
    atomicAdd(p, v);
#endif
}

// ws float layout (fast path, no zero-init needed — everything is
// fully written before it is read):
//   [0..639]                      mval: 5 x 128 matvec outputs (plain stores)
//   [640 .. 640+GRID1*128)        cpart: per-block colsum partials
//   [.. +GRID1*8)                 spart: per-block scalar partials
// scalars order: 0:Sp_h 1:Sn_h 2:Sp_hc 3:Sn_hc 4:Sp_s 5:Sn_s 6:Sp_sc 7:Sn_sc
// Fallback path (tiny ws): colsum at [640..767], scalars [768..775], atomics
// (those 136 floats are memset to 0 only in that branch).

__global__ __launch_bounds__(BLK, 8) void k_reduce(
        const float* __restrict__ muN,
        const float* __restrict__ h,  const float* __restrict__ hc,
        const float* __restrict__ s,  const float* __restrict__ sc,
        int n, float* __restrict__ ws,
        float* __restrict__ cpart, float* __restrict__ spart, int use_part)
{
    const int t  = threadIdx.x;
    const int c4 = t & 31;   // float4 column (0..31)
    const int r  = t >> 5;   // row-in-group (0..7)

    // ---- column-sum of mu_N: block covers 32 contiguous rows per iter ----
    const float4* mu4 = (const float4*)muN;
    const long gstride = 32L * GRID1;            // 65536 rows/iter over grid
    float4 a0 = make_float4(0.f,0.f,0.f,0.f), a1 = a0, a2 = a0, a3 = a0;
    long rb = (long)blockIdx.x * 32;
    for (; rb + 32 <= n; rb += gstride) {        // ~3 uniform iters at N=200000
        long q = (rb + r) * 32 + c4;
        float4 v0 = mu4[q];
        float4 v1 = mu4[q + 8  * 32];
        float4 v2 = mu4[q + 16 * 32];
        float4 v3 = mu4[q + 24 * 32];
        a0.x += v0.x; a0.y += v0.y; a0.z += v0.z; a0.w += v0.w;
        a1.x += v1.x; a1.y += v1.y; a1.z += v1.z; a1.w += v1.w;
        a2.x += v2.x; a2.y += v2.y; a2.z += v2.z; a2.w += v2.w;
        a3.x += v3.x; a3.y += v3.y; a3.z += v3.z; a3.w += v3.w;
    }
    {   // tail (no-op when n % 32 == 0)
        long q0 = rb + r;
        if (q0 < n)      { float4 v = mu4[q0*32 + c4];      a0.x+=v.x; a0.y+=v.y; a0.z+=v.z; a0.w+=v.w; }
        if (q0+8 < n)    { float4 v = mu4[(q0+8)*32 + c4];  a1.x+=v.x; a1.y+=v.y; a1.z+=v.z; a1.w+=v.w; }
        if (q0+16 < n)   { float4 v = mu4[(q0+16)*32 + c4]; a2.x+=v.x; a2.y+=v.y; a2.z+=v.z; a2.w+=v.w; }
        if (q0+24 < n)   { float4 v = mu4[(q0+24)*32 + c4]; a3.x+=v.x; a3.y+=v.y; a3.z+=v.z; a3.w+=v.w; }
    }
    a0.x += a1.x + a2.x + a3.x;
    a0.y += a1.y + a2.y + a3.y;
    a0.z += a1.z + a2.z + a3.z;
    a0.w += a1.w + a2.w + a3.w;

    __shared__ float4 red[8][32];
    red[r][c4] = a0;
    __syncthreads();
    if (r < 4) {
        float4 o = red[r+4][c4];
        red[r][c4].x += o.x; red[r][c4].y += o.y;
        red[r][c4].z += o.z; red[r][c4].w += o.w;
    }
    __syncthreads();
    if (r < 2) {
        float4 o = red[r+2][c4];
        red[r][c4].x += o.x; red[r][c4].y += o.y;
        red[r][c4].z += o.z; red[r][c4].w += o.w;
    }
    __syncthreads();
    if (r == 0) {
        float4 a = red[0][c4];
        float4 b = red[1][c4];
        float4 fin = make_float4(a.x+b.x, a.y+b.y, a.z+b.z, a.w+b.w);
        if (use_part) {
            ((float4*)cpart)[blockIdx.x * 32 + c4] = fin;   // plain coalesced store
        } else {
            atomicAddF(&ws[640 + c4*4 + 0], fin.x);
            atomicAddF(&ws[640 + c4*4 + 1], fin.y);
            atomicAddF(&ws[640 + c4*4 + 2], fin.z);
            atomicAddF(&ws[640 + c4*4 + 3], fin.w);
        }
    }

    // ---- relu-sum scalars for h, hc, s, sc ----
    float v8[8];
#pragma unroll
    for (int j = 0; j < 8; ++j) v8[j] = 0.f;
    for (int idx = blockIdx.x * BLK + t; idx < n; idx += GRID1 * BLK) {
        float vh  = h[idx],  vhc = hc[idx];
        float vs  = s[idx],  vsc = sc[idx];
        v8[0] += fmaxf(vh, 0.f);   v8[1] += fmaxf(-vh, 0.f);
        v8[2] += fmaxf(vhc, 0.f);  v8[3] += fmaxf(-vhc, 0.f);
        v8[4] += fmaxf(vs, 0.f);   v8[5] += fmaxf(-vs, 0.f);
        v8[6] += fmaxf(vsc, 0.f);  v8[7] += fmaxf(-vsc, 0.f);
    }
#pragma unroll
    for (int k = 32; k >= 1; k >>= 1) {
#pragma unroll
        for (int j = 0; j < 8; ++j) v8[j] += __shfl_xor(v8[j], k);
    }
    __shared__ float sred[4][8];
    int wave = t >> 6, lane = t & 63;
    if (lane == 0) {
#pragma unroll
        for (int j = 0; j < 8; ++j) sred[wave][j] = v8[j];
    }
    __syncthreads();
    if (t < 8) {
        float sum = sred[0][t] + sred[1][t] + sred[2][t] + sred[3][t];
        if (use_part) spart[blockIdx.x * 8 + t] = sum;
        else          atomicAddF(&ws[768 + t], sum);
    }
}

// 40 blocks: m = bid/8 picks matrix, slice = bid%8 picks 16 output rows.
// Block reduces the stage-1 partials into its input vector xs, computes its
// 16 rows, and writes them with PLAIN stores into mval[m*128+row]
// (each row owned by exactly one block -> no atomics, no zero-init).
__global__ __launch_bounds__(BLK) void k_mats(
        const float* __restrict__ W1, const float* __restrict__ W2,
        const float* __restrict__ W3, const float* __restrict__ W4,
        const float* __restrict__ W5, const float* __restrict__ W6,
        const float* __restrict__ W7, const float* __restrict__ W8,
        const float* __restrict__ W9,
        float* __restrict__ ws, const float* __restrict__ cpart,
        const float* __restrict__ spart, int use_part)
{
    const int m     = blockIdx.x >> 3;   // 0..4
    const int slice = blockIdx.x & 7;    // 0..7
    const int t = threadIdx.x;
    const int c4 = t & 31, r = t >> 5;
    const int lane = t & 63, wave = t >> 6;

    const float* Wm = (m == 0) ? W1 : (m == 1) ? W2 : (m == 2) ? W4
                    : (m == 3) ? W6 : W8;
    const float* wv = (m == 1) ? W3 : (m == 2) ? W5 : (m == 3) ? W7
                    : (m == 4) ? W9 : nullptr;

    __shared__ float xs[P];
    __shared__ float4 red[8][32];
    __shared__ float sr[2][4];

    if (m == 0) {
        if (use_part) {
            const float4* cp4 = (const float4*)cpart;
            float4 a = make_float4(0.f,0.f,0.f,0.f);
            for (int b = r; b < GRID1; b += 16) {     // 2-way ILP
                float4 v0 = cp4[b * 32 + c4];
                float4 v1 = cp4[(b + 8) * 32 + c4];
                a.x += v0.x + v1.x; a.y += v0.y + v1.y;
                a.z += v0.z + v1.z; a.w += v0.w + v1.w;
            }
            red[r][c4] = a;
            __syncthreads();
            if (r < 4) {
                float4 o = red[r+4][c4];
                red[r][c4].x += o.x; red[r][c4].y += o.y;
                red[r][c4].z += o.z; red[r][c4].w += o.w;
            }
            __syncthreads();
            if (r < 2) {
                float4 o = red[r+2][c4];
                red[r][c4].x += o.x; red[r][c4].y += o.y;
                red[r][c4].z += o.z; red[r][c4].w += o.w;
            }
            __syncthreads();
            if (r == 0) {
                float4 a2 = red[0][c4];
                float4 b2 = red[1][c4];
                ((float4*)xs)[c4] = make_float4(a2.x+b2.x, a2.y+b2.y,
                                                a2.z+b2.z, a2.w+b2.w);
            }
        } else {
            if (t < P) xs[t] = ws[640 + t];
        }
        __syncthreads();
    } else {
        float sp = 0.f, sn = 0.f;
        const int j = 2 * (m - 1);
        if (use_part) {
            for (int b = t; b < GRID1; b += BLK) {
                sp += spart[b * 8 + j];
                sn += spart[b * 8 + j + 1];
            }
#pragma unroll
            for (int k = 32; k >= 1; k >>= 1) {
                sp += __shfl_xor(sp, k);
                sn += __shfl_xor(sn, k);
            }
            if (lane == 0) { sr[0][wave] = sp; sr[1][wave] = sn; }
            __syncthreads();
            sp = sr[0][0] + sr[0][1] + sr[0][2] + sr[0][3];
            sn = sr[1][0] + sr[1][1] + sr[1][2] + sr[1][3];
        } else {
            sp = ws[768 + j];
            sn = ws[768 + j + 1];
        }
        if (t < P) {
            float w = wv[t];
            xs[t] = fmaxf(w, 0.f) * sp + fmaxf(-w, 0.f) * sn;
        }
        __syncthreads();
    }

    // ---- matvec slice: 16 output rows of Wm @ xs, plain stores ----
    const float4* W4p = (const float4*)Wm;
    const float4* xs4 = (const float4*)xs;
#pragma unroll
    for (int it = 0; it < 2; ++it) {
        int f = slice * 512 + it * 256 + t;   // float4 index into W
        int o = f >> 5;                       // output row
        float4 w = W4p[f];
        float4 x = xs4[f & 31];
        float p = w.x * x.x + w.y * x.y + w.z * x.z + w.w * x.w;
#pragma unroll
        for (int k = 16; k >= 1; k >>= 1) p += __shfl_xor(p, k);
        if ((t & 31) == 0) ws[m * P + o] = p;   // unique (m,o) per 32-group
    }
}

__global__ void k_out(const float* __restrict__ xi,
                      const float* __restrict__ W10,
                      const float* __restrict__ mval,
                      float* __restrict__ out)
{
    int t = threadIdx.x;
    if (t < P) {
        float v = mval[t] + mval[P + t] + mval[2*P + t]
                + mval[3*P + t] + mval[4*P + t]
                + W10[t * 3 + 0] * xi[0]
                + W10[t * 3 + 1] * xi[1]
                + W10[t * 3 + 2] * xi[2];
        out[t] = fmaxf(v, 0.f);
    }
}

extern "C" void kernel_launch(void* const* d_in, const int* in_sizes, int n_in,
                              void* d_out, int out_size, void* d_ws, size_t ws_size,
                              hipStream_t stream) {
    const float* xi  = (const float*)d_in[0];
    const float* muN = (const float*)d_in[1];
    const float* h   = (const float*)d_in[2];
    const float* hc  = (const float*)d_in[3];
    const float* s   = (const float*)d_in[4];
    const float* sc  = (const float*)d_in[5];
    const float* W1  = (const float*)d_in[6];
    const float* W2  = (const float*)d_in[7];
    const float* W3  = (const float*)d_in[8];
    const float* W4  = (const float*)d_in[9];
    const float* W5  = (const float*)d_in[10];
    const float* W6  = (const float*)d_in[11];
    const float* W7  = (const float*)d_in[12];
    const float* W8  = (const float*)d_in[13];
    const float* W9  = (const float*)d_in[14];
    const float* W10 = (const float*)d_in[15];
    float* ws = (float*)d_ws;
    int n = in_sizes[2];   // 200000

    const size_t need = (size_t)(640 + GRID1 * 128 + GRID1 * 8) * sizeof(float);
    const int use_part = (ws_size >= need) ? 1 : 0;   // call-invariant -> graph-stable
    float* cpart = ws + 640;
    float* spart = ws + 640 + GRID1 * 128;

    if (!use_part)   // atomic fallback needs zeroed accumulators
        hipMemsetAsync(ws + 640, 0, 136 * sizeof(float), stream);

    k_reduce<<<GRID1, BLK, 0, stream>>>(muN, h, hc, s, sc, n, ws,
                                        cpart, spart, use_part);
    k_mats<<<40, BLK, 0, stream>>>(W1, W2, W3, W4, W5, W6, W7, W8, W9,
                                   ws, cpart, spart, use_part);
    k_out<<<1, 128, 0, stream>>>(xi, W10, ws, (float*)d_out);
}

// Round 5
// 201.599 us; speedup vs baseline: 1.1013x; 1.1013x over previous
//
#include <hip/hip_runtime.h>

#define P 128
#define GRID1 1024
#define BLK 256

__device__ __forceinline__ void atomicAddF(float* p, float v) {
#if defined(__HIP_DEVICE_COMPILE__)
    unsafeAtomicAdd(p, v);   // global_atomic_add_f32 on gfx950
#else
    atomicAdd(p, v);
#endif
}

// ws float layout (fast path, no zero-init needed — everything is
// fully written before it is read):
//   [0..639]                      mval: 5 x 128 matvec outputs (plain stores)
//   [640 .. 640+GRID1*128)        cpart: per-block colsum partials
//   [.. +GRID1*8)                 spart: per-block scalar partials
// scalars order: 0:Sp_h 1:Sn_h 2:Sp_hc 3:Sn_hc 4:Sp_s 5:Sn_s 6:Sp_sc 7:Sn_sc
// Fallback path (tiny ws): colsum at [640..767], scalars [768..775], atomics
// (those 136 floats are memset to 0 only in that branch).

__global__ __launch_bounds__(BLK) void k_reduce(
        const float* __restrict__ muN,
        const float* __restrict__ h,  const float* __restrict__ hc,
        const float* __restrict__ s,  const float* __restrict__ sc,
        int n, float* __restrict__ ws,
        float* __restrict__ cpart, float* __restrict__ spart, int use_part)
{
    const int t  = threadIdx.x;
    const int c4 = t & 31;   // float4 column (0..31)
    const int r  = t >> 5;   // row-in-group (0..7)

    // ---- column-sum of mu_N: block covers 32 contiguous rows per iter ----
    const float4* mu4 = (const float4*)muN;
    const long gstride = 32L * GRID1;            // 32768 rows/iter over grid
    float4 a0 = make_float4(0.f,0.f,0.f,0.f), a1 = a0, a2 = a0, a3 = a0;
    long rb = (long)blockIdx.x * 32;
    for (; rb + 32 <= n; rb += gstride) {        // ~6 uniform iters at N=200000
        long q = (rb + r) * 32 + c4;
        float4 v0 = mu4[q];
        float4 v1 = mu4[q + 8  * 32];
        float4 v2 = mu4[q + 16 * 32];
        float4 v3 = mu4[q + 24 * 32];
        a0.x += v0.x; a0.y += v0.y; a0.z += v0.z; a0.w += v0.w;
        a1.x += v1.x; a1.y += v1.y; a1.z += v1.z; a1.w += v1.w;
        a2.x += v2.x; a2.y += v2.y; a2.z += v2.z; a2.w += v2.w;
        a3.x += v3.x; a3.y += v3.y; a3.z += v3.z; a3.w += v3.w;
    }
    {   // tail (no-op when n % 32 == 0)
        long q0 = rb + r;
        if (q0 < n)      { float4 v = mu4[q0*32 + c4];      a0.x+=v.x; a0.y+=v.y; a0.z+=v.z; a0.w+=v.w; }
        if (q0+8 < n)    { float4 v = mu4[(q0+8)*32 + c4];  a1.x+=v.x; a1.y+=v.y; a1.z+=v.z; a1.w+=v.w; }
        if (q0+16 < n)   { float4 v = mu4[(q0+16)*32 + c4]; a2.x+=v.x; a2.y+=v.y; a2.z+=v.z; a2.w+=v.w; }
        if (q0+24 < n)   { float4 v = mu4[(q0+24)*32 + c4]; a3.x+=v.x; a3.y+=v.y; a3.z+=v.z; a3.w+=v.w; }
    }
    a0.x += a1.x + a2.x + a3.x;
    a0.y += a1.y + a2.y + a3.y;
    a0.z += a1.z + a2.z + a3.z;
    a0.w += a1.w + a2.w + a3.w;

    __shared__ float4 red[8][32];
    red[r][c4] = a0;
    __syncthreads();
    if (r < 4) {
        float4 o = red[r+4][c4];
        red[r][c4].x += o.x; red[r][c4].y += o.y;
        red[r][c4].z += o.z; red[r][c4].w += o.w;
    }
    __syncthreads();
    if (r < 2) {
        float4 o = red[r+2][c4];
        red[r][c4].x += o.x; red[r][c4].y += o.y;
        red[r][c4].z += o.z; red[r][c4].w += o.w;
    }
    __syncthreads();
    if (r == 0) {
        float4 a = red[0][c4];
        float4 b = red[1][c4];
        float4 fin = make_float4(a.x+b.x, a.y+b.y, a.z+b.z, a.w+b.w);
        if (use_part) {
            ((float4*)cpart)[blockIdx.x * 32 + c4] = fin;   // plain coalesced store
        } else {
            atomicAddF(&ws[640 + c4*4 + 0], fin.x);
            atomicAddF(&ws[640 + c4*4 + 1], fin.y);
            atomicAddF(&ws[640 + c4*4 + 2], fin.z);
            atomicAddF(&ws[640 + c4*4 + 3], fin.w);
        }
    }

    // ---- relu-sum scalars for h, hc, s, sc ----
    float v8[8];
#pragma unroll
    for (int j = 0; j < 8; ++j) v8[j] = 0.f;
    for (int idx = blockIdx.x * BLK + t; idx < n; idx += GRID1 * BLK) {
        float vh  = h[idx],  vhc = hc[idx];
        float vs  = s[idx],  vsc = sc[idx];
        v8[0] += fmaxf(vh, 0.f);   v8[1] += fmaxf(-vh, 0.f);
        v8[2] += fmaxf(vhc, 0.f);  v8[3] += fmaxf(-vhc, 0.f);
        v8[4] += fmaxf(vs, 0.f);   v8[5] += fmaxf(-vs, 0.f);
        v8[6] += fmaxf(vsc, 0.f);  v8[7] += fmaxf(-vsc, 0.f);
    }
#pragma unroll
    for (int k = 32; k >= 1; k >>= 1) {
#pragma unroll
        for (int j = 0; j < 8; ++j) v8[j] += __shfl_xor(v8[j], k);
    }
    __shared__ float sred[4][8];
    int wave = t >> 6, lane = t & 63;
    if (lane == 0) {
#pragma unroll
        for (int j = 0; j < 8; ++j) sred[wave][j] = v8[j];
    }
    __syncthreads();
    if (t < 8) {
        float sum = sred[0][t] + sred[1][t] + sred[2][t] + sred[3][t];
        if (use_part) spart[blockIdx.x * 8 + t] = sum;
        else          atomicAddF(&ws[768 + t], sum);
    }
}

// 40 blocks: m = bid/8 picks matrix, slice = bid%8 picks 16 output rows.
// Block reduces the stage-1 partials into its input vector xs, computes its
// 16 rows, and writes them with PLAIN stores into mval[m*128+row]
// (each row owned by exactly one block -> no atomics, no zero-init).
__global__ __launch_bounds__(BLK) void k_mats(
        const float* __restrict__ W1, const float* __restrict__ W2,
        const float* __restrict__ W3, const float* __restrict__ W4,
        const float* __restrict__ W5, const float* __restrict__ W6,
        const float* __restrict__ W7, const float* __restrict__ W8,
        const float* __restrict__ W9,
        float* __restrict__ ws, const float* __restrict__ cpart,
        const float* __restrict__ spart, int use_part)
{
    const int m     = blockIdx.x >> 3;   // 0..4
    const int slice = blockIdx.x & 7;    // 0..7
    const int t = threadIdx.x;
    const int c4 = t & 31, r = t >> 5;
    const int lane = t & 63, wave = t >> 6;

    const float* Wm = (m == 0) ? W1 : (m == 1) ? W2 : (m == 2) ? W4
                    : (m == 3) ? W6 : W8;
    const float* wv = (m == 1) ? W3 : (m == 2) ? W5 : (m == 3) ? W7
                    : (m == 4) ? W9 : nullptr;

    __shared__ float xs[P];
    __shared__ float4 red[8][32];
    __shared__ float sr[2][4];

    if (m == 0) {
        if (use_part) {
            const float4* cp4 = (const float4*)cpart;
            float4 a = make_float4(0.f,0.f,0.f,0.f);
            for (int b = r; b < GRID1; b += 16) {     // 2-way ILP
                float4 v0 = cp4[b * 32 + c4];
                float4 v1 = cp4[(b + 8) * 32 + c4];
                a.x += v0.x + v1.x; a.y += v0.y + v1.y;
                a.z += v0.z + v1.z; a.w += v0.w + v1.w;
            }
            red[r][c4] = a;
            __syncthreads();
            if (r < 4) {
                float4 o = red[r+4][c4];
                red[r][c4].x += o.x; red[r][c4].y += o.y;
                red[r][c4].z += o.z; red[r][c4].w += o.w;
            }
            __syncthreads();
            if (r < 2) {
                float4 o = red[r+2][c4];
                red[r][c4].x += o.x; red[r][c4].y += o.y;
                red[r][c4].z += o.z; red[r][c4].w += o.w;
            }
            __syncthreads();
            if (r == 0) {
                float4 a2 = red[0][c4];
                float4 b2 = red[1][c4];
                ((float4*)xs)[c4] = make_float4(a2.x+b2.x, a2.y+b2.y,
                                                a2.z+b2.z, a2.w+b2.w);
            }
        } else {
            if (t < P) xs[t] = ws[640 + t];
        }
        __syncthreads();
    } else {
        float sp = 0.f, sn = 0.f;
        const int j = 2 * (m - 1);
        if (use_part) {
            for (int b = t; b < GRID1; b += BLK) {
                sp += spart[b * 8 + j];
                sn += spart[b * 8 + j + 1];
            }
#pragma unroll
            for (int k = 32; k >= 1; k >>= 1) {
                sp += __shfl_xor(sp, k);
                sn += __shfl_xor(sn, k);
            }
            if (lane == 0) { sr[0][wave] = sp; sr[1][wave] = sn; }
            __syncthreads();
            sp = sr[0][0] + sr[0][1] + sr[0][2] + sr[0][3];
            sn = sr[1][0] + sr[1][1] + sr[1][2] + sr[1][3];
        } else {
            sp = ws[768 + j];
            sn = ws[768 + j + 1];
        }
        if (t < P) {
            float w = wv[t];
            xs[t] = fmaxf(w, 0.f) * sp + fmaxf(-w, 0.f) * sn;
        }
        __syncthreads();
    }

    // ---- matvec slice: 16 output rows of Wm @ xs, plain stores ----
    const float4* W4p = (const float4*)Wm;
    const float4* xs4 = (const float4*)xs;
#pragma unroll
    for (int it = 0; it < 2; ++it) {
        int f = slice * 512 + it * 256 + t;   // float4 index into W
        int o = f >> 5;                       // output row
        float4 w = W4p[f];
        float4 x = xs4[f & 31];
        float p = w.x * x.x + w.y * x.y + w.z * x.z + w.w * x.w;
#pragma unroll
        for (int k = 16; k >= 1; k >>= 1) p += __shfl_xor(p, k);
        if ((t & 31) == 0) ws[m * P + o] = p;   // unique (m,o) per 32-group
    }
}

__global__ void k_out(const float* __restrict__ xi,
                      const float* __restrict__ W10,
                      const float* __restrict__ mval,
                      float* __restrict__ out)
{
    int t = threadIdx.x;
    if (t < P) {
        float v = mval[t] + mval[P + t] + mval[2*P + t]
                + mval[3*P + t] + mval[4*P + t]
                + W10[t * 3 + 0] * xi[0]
                + W10[t * 3 + 1] * xi[1]
                + W10[t * 3 + 2] * xi[2];
        out[t] = fmaxf(v, 0.f);
    }
}

extern "C" void kernel_launch(void* const* d_in, const int* in_sizes, int n_in,
                              void* d_out, int out_size, void* d_ws, size_t ws_size,
                              hipStream_t stream) {
    const float* xi  = (const float*)d_in[0];
    const float* muN = (const float*)d_in[1];
    const float* h   = (const float*)d_in[2];
    const float* hc  = (const float*)d_in[3];
    const float* s   = (const float*)d_in[4];
    const float* sc  = (const float*)d_in[5];
    const float* W1  = (const float*)d_in[6];
    const float* W2  = (const float*)d_in[7];
    const float* W3  = (const float*)d_in[8];
    const float* W4  = (const float*)d_in[9];
    const float* W5  = (const float*)d_in[10];
    const float* W6  = (const float*)d_in[11];
    const float* W7  = (const float*)d_in[12];
    const float* W8  = (const float*)d_in[13];
    const float* W9  = (const float*)d_in[14];
    const float* W10 = (const float*)d_in[15];
    float* ws = (float*)d_ws;
    int n = in_sizes[2];   // 200000

    const size_t need = (size_t)(640 + GRID1 * 128 + GRID1 * 8) * sizeof(float);
    const int use_part = (ws_size >= need) ? 1 : 0;   // call-invariant -> graph-stable
    float* cpart = ws + 640;
    float* spart = ws + 640 + GRID1 * 128;

    if (!use_part)   // atomic fallback needs zeroed accumulators
        hipMemsetAsync(ws + 640, 0, 136 * sizeof(float), stream);

    k_reduce<<<GRID1, BLK, 0, stream>>>(muN, h, hc, s, sc, n, ws,
                                        cpart, spart, use_part);
    k_mats<<<40, BLK, 0, stream>>>(W1, W2, W3, W4, W5, W6, W7, W8, W9,
                                   ws, cpart, spart, use_part);
    k_out<<<1, 128, 0, stream>>>(xi, W10, ws, (float*)d_out);
}